// Round 2
// baseline (393.401 us; speedup 1.0000x reference)
//
#include <hip/hip_runtime.h>
#include <math.h>

#define TSEQ   2048
#define NBATCH 4
#define NHEAD  16
#define HDIM   64
#define DMODEL 1024
#define MROWS  (NBATCH * TSEQ)   // 8192
// fold 8 * log2(e) into Q so softmax runs in exp2 domain (v_exp_f32 native)
#define QSCALE 11.541560327111707f

typedef float f32x4  __attribute__((ext_vector_type(4)));
typedef short bf16x8 __attribute__((ext_vector_type(8)));
typedef _Float16 f16x8 __attribute__((ext_vector_type(8)));

static __device__ __forceinline__ short f2bf(float f) {  // RNE float->bf16
    union { float f; unsigned u; } a; a.f = f;
    unsigned r = a.u + 0x7FFFu + ((a.u >> 16) & 1u);
    return (short)(r >> 16);
}
static __device__ __forceinline__ float bf2f(short s) {
    union { unsigned u; float f; } a; a.u = ((unsigned)(unsigned short)s) << 16;
    return a.f;
}

// async global->LDS, 16B per lane; LDS dest = wave-uniform base + lane*16
static __device__ __forceinline__ void async_copy16(void* lds, const void* g) {
    __builtin_amdgcn_global_load_lds(
        (const __attribute__((address_space(1))) void*)g,
        (__attribute__((address_space(3))) void*)lds, 16, 0, 0);
}

// ---------------------------------------------------------------------------
// One fused fp32 -> (hi,lo) bf16 splitter for X, Wq, Wk, Wv.
// ---------------------------------------------------------------------------
#define X_F4 (MROWS * DMODEL / 4)          // 2097152
#define W_F4 (DMODEL * DMODEL / 4)         // 262144  (1<<18)
__global__ __launch_bounds__(256) void split_all(
    const float* __restrict__ x,
    const float* __restrict__ wq, const float* __restrict__ wk,
    const float* __restrict__ wv,
    short* __restrict__ Xhi, short* __restrict__ Xlo,
    short* __restrict__ Whi, short* __restrict__ Wlo)
{
    int gid = blockIdx.x * 256 + threadIdx.x;
    const float* src; short* dh; short* dl; int off;
    if (gid < X_F4) {
        src = x; dh = Xhi; dl = Xlo; off = gid;
    } else {
        int r = gid - X_F4;
        int z = r >> 18;                   // 0..2
        off = r & (W_F4 - 1);
        src = (z == 0) ? wq : (z == 1) ? wk : wv;
        dh = Whi + (size_t)z * DMODEL * DMODEL;
        dl = Wlo + (size_t)z * DMODEL * DMODEL;
    }
    float4 v = ((const float4*)src)[off];
    float f[4] = {v.x, v.y, v.z, v.w};
    short h[4], l[4];
    #pragma unroll
    for (int c = 0; c < 4; c++) {
        h[c] = f2bf(f[c]);
        l[c] = f2bf(f[c] - bf2f(h[c]));
    }
    *(float2*)(dh + (size_t)off * 4) = *(const float2*)h;
    *(float2*)(dl + (size_t)off * 4) = *(const float2*)l;
}

// ---------------------------------------------------------------------------
// Split-bf16 MFMA GEMM: Y = X W^T + b.
// z=0 -> Qhi/Qlo bf16 [bh][T][64] (scaled by QSCALE)   3-MFMA split
// z=1 -> Khi/Klo bf16 [bh][T][64]                      3-MFMA split
// z=2 -> V^T   fp16  [bh][64][T]   single bf16 MFMA
// R1: minimum 2-phase prefetch (T3 recipe) — stage K-tile t+1 into buf^1
//     BEFORE computing tile t, so global_load_lds latency hides under the
//     MFMA phase instead of being serially exposed each K-step.
//     LDS 32->64 KB, still 2 blocks/CU.
// ---------------------------------------------------------------------------
__global__ __launch_bounds__(256, 2) void qkv_gemm_mfma(
    const short* __restrict__ Xhi, const short* __restrict__ Xlo,
    const short* __restrict__ Wh3, const short* __restrict__ Wl3,  // [3][N][K]
    const float* __restrict__ bq, const float* __restrict__ bk,
    const float* __restrict__ bv,
    short* __restrict__ Qhi, short* __restrict__ Qlo,
    short* __restrict__ Khi, short* __restrict__ Klo,
    _Float16* __restrict__ VgT)
{
    const int z = blockIdx.z;
    const bool dolo = (z != 2);
    const short* Wh = Wh3 + (size_t)z * DMODEL * DMODEL;
    const short* Wl = Wl3 + (size_t)z * DMODEL * DMODEL;
    const float* bias = (z == 0) ? bq : (z == 1) ? bk : bv;

    __shared__ __align__(16) short Ah[2][128 * 32];
    __shared__ __align__(16) short Al[2][128 * 32];
    __shared__ __align__(16) short Bh[2][128 * 32];
    __shared__ __align__(16) short Bl[2][128 * 32];

    const int tid  = threadIdx.x;
    const int w    = tid >> 6;
    const int lane = tid & 63;
    const int t    = lane & 15;
    const int quad = lane >> 4;
    const int wm   = w >> 1, wn = w & 1;
    const int bm   = blockIdx.y * 128;
    const int bn   = blockIdx.x * 128;

    const int r_local = lane >> 2;
    const int kq      = (lane & 3) ^ ((r_local >> 1) & 3);
    const int row0    = w * 32 + r_local;
    const int slotq   = (quad ^ ((t >> 1) & 3)) * 8;

    f32x4 acc[4][4];
    #pragma unroll
    for (int i = 0; i < 4; i++)
        #pragma unroll
        for (int j = 0; j < 4; j++) acc[i][j] = (f32x4){0.f, 0.f, 0.f, 0.f};

    auto stage = [&](int k0, int bf) {
        #pragma unroll
        for (int i = 0; i < 2; i++) {
            int row = row0 + i * 16;
            size_t ga = (size_t)(bm + row) * DMODEL + k0 + kq * 8;
            size_t gb = (size_t)(bn + row) * DMODEL + k0 + kq * 8;
            int ldst = (w * 32 + i * 16) * 32;
            async_copy16(&Ah[bf][ldst], Xhi + ga);
            async_copy16(&Bh[bf][ldst], Wh + gb);
            if (dolo) {
                async_copy16(&Al[bf][ldst], Xlo + ga);
                async_copy16(&Bl[bf][ldst], Wl + gb);
            }
        }
    };

    // prologue: stage tile 0, drain
    stage(0, 0);
    __syncthreads();

    int cur = 0;
    for (int k0 = 0; k0 < DMODEL; k0 += 32) {
        // issue next tile's loads FIRST — they drain at the barrier below,
        // after the MFMA phase has covered their latency
        if (k0 + 32 < DMODEL) stage(k0 + 32, cur ^ 1);

        bf16x8 ah[4], al[4], bh[4], bl[4];
        #pragma unroll
        for (int mt = 0; mt < 4; mt++) {
            int off = (wm * 64 + mt * 16 + t) * 32 + slotq;
            ah[mt] = *(const bf16x8*)&Ah[cur][off];
            if (dolo) al[mt] = *(const bf16x8*)&Al[cur][off];
        }
        #pragma unroll
        for (int nt = 0; nt < 4; nt++) {
            int off = (wn * 64 + nt * 16 + t) * 32 + slotq;
            bh[nt] = *(const bf16x8*)&Bh[cur][off];
            if (dolo) bl[nt] = *(const bf16x8*)&Bl[cur][off];
        }
        #pragma unroll
        for (int mt = 0; mt < 4; mt++)
            #pragma unroll
            for (int nt = 0; nt < 4; nt++) {
                if (dolo) {
                    acc[mt][nt] = __builtin_amdgcn_mfma_f32_16x16x32_bf16(
                        al[mt], bh[nt], acc[mt][nt], 0, 0, 0);
                    acc[mt][nt] = __builtin_amdgcn_mfma_f32_16x16x32_bf16(
                        ah[mt], bl[nt], acc[mt][nt], 0, 0, 0);
                }
                acc[mt][nt] = __builtin_amdgcn_mfma_f32_16x16x32_bf16(
                    ah[mt], bh[nt], acc[mt][nt], 0, 0, 0);
            }

        // one barrier per K-step: orders this iter's LDS reads before the
        // next iter's overwrite, and drains the prefetch (vmcnt(0) implicit)
        __syncthreads();
        cur ^= 1;
    }

    const float scale = (z == 0) ? QSCALE : 1.0f;
    const int n_base = bn + wn * 64;
    const int h_head = n_base >> 6;
    float bvs[4];
    #pragma unroll
    for (int nt = 0; nt < 4; nt++)
        bvs[nt] = bias[n_base + nt * 16 + t];

    #pragma unroll
    for (int mt = 0; mt < 4; mt++) {
        #pragma unroll
        for (int r = 0; r < 4; r++) {
            int m  = bm + wm * 64 + mt * 16 + quad * 4 + r;
            int b_ = m >> 11;
            int t_ = m & 2047;
            #pragma unroll
            for (int nt = 0; nt < 4; nt++) {
                int d = nt * 16 + t;
                float v = (acc[mt][nt][r] + bvs[nt]) * scale;
                if (z == 2) {
                    size_t idx = ((size_t)(b_ * NHEAD + h_head) * HDIM + d) * TSEQ + t_;
                    VgT[idx] = (_Float16)v;
                } else {
                    size_t idx = (((size_t)(b_ * NHEAD + h_head) * TSEQ + t_) << 6) + d;
                    short hb = f2bf(v);
                    short lb = f2bf(v - bf2f(hb));
                    if (z == 0) { Qhi[idx] = hb; Qlo[idx] = lb; }
                    else        { Khi[idx] = hb; Klo[idx] = lb; }
                }
            }
        }
    }
}

// ---------------------------------------------------------------------------
// MFMA flash attention v5 — pair-batched softmax + BALANCED GRID.
//  Block (i, bh), i in [0,8): processes Q-tile i (i+1 pairs) then Q-tile
//  15-i (16-i pairs) -> every block does exactly 17 pair-units.
//  Grid 8x64 = 512 blocks = exactly 2/CU co-resident: no triangular tail,
//  time-avg occupancy pinned at the LDS cap.
// LDS: 2*(8+8+8) + 18 = 66 KB -> 2 blocks/CU.
// ---------------------------------------------------------------------------
__global__ __launch_bounds__(256, 2) void attn_fwd(
    const short* __restrict__ Qhi, const short* __restrict__ Qlo,
    const short* __restrict__ Khi, const short* __restrict__ Klo,
    const _Float16* __restrict__ VgT,   // [bh][64][T]
    float* __restrict__ out)            // [B][T][1024]
{
    __shared__ __align__(16) short    Kh_lds[2][64 * 64];
    __shared__ __align__(16) short    Kl_lds[2][64 * 64];
    __shared__ __align__(16) _Float16 Vt_lds[2][64 * 64];
    __shared__ __align__(16) _Float16 P_lds [128 * 72];

    const int tid  = threadIdx.x;
    const int bh   = blockIdx.y;
    const int b    = bh >> 4, h = bh & 15;
    const int w    = tid >> 6;
    const int lane = tid & 63;
    const int t    = lane & 15;
    const int quad = lane >> 4;

    // staging geometry: per round, 256 lanes x 16B = 32 rows of 128B.
    const int rl      = w * 8 + (lane >> 3);         // 0..31 within round
    const int chsw    = (lane & 7) ^ ((lane >> 3) & 7);
    const int ld_off  = (w * 8) * 64;                // wave-uniform LDS base

    const size_t kbase = (size_t)bh * TSEQ;          // K rows
    const size_t vbase = (size_t)bh * HDIM;          // V^T rows

    // read-side swizzled chunk offsets: chunk g=dh*4+quad at slot g^(t&7)
    const int rs0 = ((0 * 4 + quad) ^ (t & 7)) * 8;
    const int rs1 = ((1 * 4 + quad) ^ (t & 7)) * 8;

    f16x8 ones;
    #pragma unroll
    for (int i = 0; i < 8; i++) ones[i] = (_Float16)1.0f;

    auto stage = [&](int kt, int bf) {
        #pragma unroll
        for (int i = 0; i < 2; i++) {
            int row = i * 32 + rl;
            const short* gk = Khi + (kbase + kt * 64 + row) * 64 + chsw * 8;
            async_copy16(&Kh_lds[bf][(i * 32) * 64 + ld_off], gk);
            const short* gl = Klo + (kbase + kt * 64 + row) * 64 + chsw * 8;
            async_copy16(&Kl_lds[bf][(i * 32) * 64 + ld_off], gl);
            const _Float16* gv = VgT + (vbase + row) * TSEQ + kt * 64 + chsw * 8;
            async_copy16(&Vt_lds[bf][(i * 32) * 64 + ld_off], gv);
        }
    };

    // two complementary Q-tile segments: i+1 pairs, then 16-i pairs (17 total)
    #pragma unroll 1
    for (int seg = 0; seg < 2; seg++) {
        const int qb = seg ? (15 - blockIdx.x) : blockIdx.x;

        // Q A-frags for this segment
        bf16x8 qh[2][2], ql[2][2];
        #pragma unroll
        for (int mt = 0; mt < 2; mt++) {
            size_t qrow = kbase + qb * 128 + w * 32 + mt * 16 + t;
            #pragma unroll
            for (int dh = 0; dh < 2; dh++) {
                qh[mt][dh] = *(const bf16x8*)(Qhi + qrow * 64 + dh * 32 + quad * 8);
                ql[mt][dh] = *(const bf16x8*)(Qlo + qrow * 64 + dh * 32 + quad * 8);
            }
        }

        f32x4 O[2][4], Ol[2];
        #pragma unroll
        for (int mt = 0; mt < 2; mt++) {
            Ol[mt] = (f32x4){0.f, 0.f, 0.f, 0.f};
            #pragma unroll
            for (int j = 0; j < 4; j++) O[mt][j] = (f32x4){0.f, 0.f, 0.f, 0.f};
        }
        float m_st[2][4];
        #pragma unroll
        for (int mt = 0; mt < 2; mt++)
            #pragma unroll
            for (int r = 0; r < 4; r++) m_st[mt][r] = -1e30f;

        const int npair = qb + 1;

        #pragma unroll 1
        for (int p = 0; p < npair; p++) {
            __syncthreads();              // previous pair's LDS reads complete
            stage(2 * p, 0);
            stage(2 * p + 1, 1);
            __syncthreads();              // drain the 12 async copies

            #pragma unroll
            for (int mt = 0; mt < 2; mt++) {
                // ---- S over 128 cols: c8=0..3 from buf0, 4..7 from buf1 ----
                f32x4 S[8];
                #pragma unroll
                for (int c8 = 0; c8 < 8; c8++) {
                    S[c8] = (f32x4){0.f, 0.f, 0.f, 0.f};
                    const int bf = c8 >> 2;
                    const int rowoff = ((c8 & 3) * 16 + t) * 64;
                    {
                        bf16x8 kh = *(const bf16x8*)&Kh_lds[bf][rowoff + rs0];
                        bf16x8 kl = *(const bf16x8*)&Kl_lds[bf][rowoff + rs0];
                        S[c8] = __builtin_amdgcn_mfma_f32_16x16x32_bf16(ql[mt][0], kh, S[c8], 0, 0, 0);
                        S[c8] = __builtin_amdgcn_mfma_f32_16x16x32_bf16(qh[mt][0], kl, S[c8], 0, 0, 0);
                        S[c8] = __builtin_amdgcn_mfma_f32_16x16x32_bf16(qh[mt][0], kh, S[c8], 0, 0, 0);
                    }
                    {
                        bf16x8 kh = *(const bf16x8*)&Kh_lds[bf][rowoff + rs1];
                        bf16x8 kl = *(const bf16x8*)&Kl_lds[bf][rowoff + rs1];
                        S[c8] = __builtin_amdgcn_mfma_f32_16x16x32_bf16(ql[mt][1], kh, S[c8], 0, 0, 0);
                        S[c8] = __builtin_amdgcn_mfma_f32_16x16x32_bf16(qh[mt][1], kl, S[c8], 0, 0, 0);
                        S[c8] = __builtin_amdgcn_mfma_f32_16x16x32_bf16(qh[mt][1], kh, S[c8], 0, 0, 0);
                    }
                }

                // causal mask (only the last pair contains the diagonal)
                if (p == qb) {
                    #pragma unroll
                    for (int c8 = 0; c8 < 8; c8++) {
                        int col = c8 * 16 + t;
                        #pragma unroll
                        for (int r = 0; r < 4; r++)
                            if (col > w * 32 + mt * 16 + quad * 4 + r) S[c8][r] = -1e30f;
                    }
                }

                // ---- ONE max-reduce + (conditional) rescale per 128 cols ----
                float mx[4]; bool grow = false;
                #pragma unroll
                for (int r = 0; r < 4; r++) {
                    float a0 = fmaxf(fmaxf(S[0][r], S[1][r]), fmaxf(S[2][r], S[3][r]));
                    float a1 = fmaxf(fmaxf(S[4][r], S[5][r]), fmaxf(S[6][r], S[7][r]));
                    float v = fmaxf(a0, a1);
                    v = fmaxf(v, __shfl_xor(v, 1, 64));
                    v = fmaxf(v, __shfl_xor(v, 2, 64));
                    v = fmaxf(v, __shfl_xor(v, 4, 64));
                    v = fmaxf(v, __shfl_xor(v, 8, 64));
                    mx[r] = v;
                    grow = grow || (v > m_st[mt][r]);
                }
                if (__ballot(grow)) {
                    #pragma unroll
                    for (int r = 0; r < 4; r++) {
                        float mn = fmaxf(m_st[mt][r], mx[r]);
                        float al = exp2f(m_st[mt][r] - mn);
                        m_st[mt][r] = mn;
                        Ol[mt][r] *= al;
                        #pragma unroll
                        for (int ct2 = 0; ct2 < 4; ct2++) O[mt][ct2][r] *= al;
                    }
                }
                #pragma unroll
                for (int c8 = 0; c8 < 8; c8++)
                    #pragma unroll
                    for (int r = 0; r < 4; r++)
                        S[c8][r] = exp2f(S[c8][r] - m_st[mt][r]);

                // ---- PV in two halves, reusing the wave-private P strip ----
                const int prow = w * 32 + mt * 16;
                #pragma unroll
                for (int half = 0; half < 2; half++) {
                    #pragma unroll
                    for (int ct = 0; ct < 4; ct++)
                        #pragma unroll
                        for (int r = 0; r < 4; r++)
                            P_lds[(prow + quad * 4 + r) * 72 + ct * 16 + t] =
                                (_Float16)S[half * 4 + ct][r];
                    f16x8 p0 = *(const f16x8*)&P_lds[(prow + t) * 72 + quad * 8];
                    f16x8 p1 = *(const f16x8*)&P_lds[(prow + t) * 72 + 32 + quad * 8];
                    #pragma unroll
                    for (int ct2 = 0; ct2 < 4; ct2++) {
                        int rowoff2 = (ct2 * 16 + t) * 64;
                        f16x8 v0 = *(const f16x8*)&Vt_lds[half][rowoff2 + rs0];
                        f16x8 v1 = *(const f16x8*)&Vt_lds[half][rowoff2 + rs1];
                        O[mt][ct2] = __builtin_amdgcn_mfma_f32_16x16x32_f16(p0, v0, O[mt][ct2], 0, 0, 0);
                        O[mt][ct2] = __builtin_amdgcn_mfma_f32_16x16x32_f16(p1, v1, O[mt][ct2], 0, 0, 0);
                    }
                    Ol[mt] = __builtin_amdgcn_mfma_f32_16x16x32_f16(p0, ones, Ol[mt], 0, 0, 0);
                    Ol[mt] = __builtin_amdgcn_mfma_f32_16x16x32_f16(p1, ones, Ol[mt], 0, 0, 0);
                }
            }
        }

        // epilogue: normalize, write [B][T][H*64] fp32
        #pragma unroll
        for (int mt = 0; mt < 2; mt++) {
            float* ob = out + ((size_t)b * TSEQ + qb * 128 + w * 32 + mt * 16 + quad * 4) * DMODEL
                      + h * 64;
            #pragma unroll
            for (int r = 0; r < 4; r++) {
                float inv = 1.0f / Ol[mt][r];
                #pragma unroll
                for (int ct2 = 0; ct2 < 4; ct2++)
                    ob[(size_t)r * DMODEL + ct2 * 16 + t] = O[mt][ct2][r] * inv;
            }
        }
    }
}

// ---------------------------------------------------------------------------
extern "C" void kernel_launch(void* const* d_in, const int* in_sizes, int n_in,
                              void* d_out, int out_size, void* d_ws, size_t ws_size,
                              hipStream_t stream)
{
    const float* x  = (const float*)d_in[0];
    const float* Wq = (const float*)d_in[1];
    const float* bq = (const float*)d_in[2];
    const float* Wk = (const float*)d_in[3];
    const float* bk = (const float*)d_in[4];
    const float* Wv = (const float*)d_in[5];
    const float* bv = (const float*)d_in[6];

    const size_t TEN = (size_t)MROWS * DMODEL;   // 8M
    const size_t WEN = (size_t)DMODEL * DMODEL;  // 1M
    short* Xhi = (short*)d_ws;
    short* Xlo = Xhi + TEN;
    short* Whi = Xlo + TEN;
    short* Wlo = Whi + 3 * WEN;
    short* Qhi = Wlo + 3 * WEN;
    short* Qlo = Qhi + TEN;
    short* Khi = Qlo + TEN;
    short* Klo = Khi + TEN;
    _Float16* VgT = (_Float16*)(Klo + TEN);
    float* out = (float*)d_out;

    int nsplit = (X_F4 + 3 * W_F4) / 256;
    split_all<<<nsplit, 256, 0, stream>>>(x, Wq, Wk, Wv, Xhi, Xlo, Whi, Wlo);

    dim3 gg(DMODEL / 128, MROWS / 128, 3);
    qkv_gemm_mfma<<<gg, 256, 0, stream>>>(Xhi, Xlo, Whi, Wlo, bq, bk, bv,
                                          Qhi, Qlo, Khi, Klo, VgT);

    dim3 ga(8, NBATCH * NHEAD);
    attn_fwd<<<ga, 256, 0, stream>>>(Qhi, Qlo, Khi, Klo, VgT, out);
}

// Round 3
// 360.675 us; speedup vs baseline: 1.0907x; 1.0907x over previous
//
#include <hip/hip_runtime.h>
#include <math.h>

#define TSEQ   2048
#define NBATCH 4
#define NHEAD  16
#define HDIM   64
#define DMODEL 1024
#define MROWS  (NBATCH * TSEQ)   // 8192
// fold 8 * log2(e) into Q so softmax runs in exp2 domain (v_exp_f32 native)
#define QSCALE 11.541560327111707f

typedef float f32x4  __attribute__((ext_vector_type(4)));
typedef short bf16x8 __attribute__((ext_vector_type(8)));
typedef _Float16 f16x8 __attribute__((ext_vector_type(8)));

static __device__ __forceinline__ short f2bf(float f) {  // RNE float->bf16
    union { float f; unsigned u; } a; a.f = f;
    unsigned r = a.u + 0x7FFFu + ((a.u >> 16) & 1u);
    return (short)(r >> 16);
}
static __device__ __forceinline__ float bf2f(short s) {
    union { unsigned u; float f; } a; a.u = ((unsigned)(unsigned short)s) << 16;
    return a.f;
}

// async global->LDS, 16B per lane; LDS dest = wave-uniform base + lane*16
static __device__ __forceinline__ void async_copy16(void* lds, const void* g) {
    __builtin_amdgcn_global_load_lds(
        (const __attribute__((address_space(1))) void*)g,
        (__attribute__((address_space(3))) void*)lds, 16, 0, 0);
}

// ---------------------------------------------------------------------------
// One fused fp32 -> (hi,lo) bf16 splitter for X, Wq, Wk, Wv.
// ---------------------------------------------------------------------------
#define X_F4 (MROWS * DMODEL / 4)          // 2097152
#define W_F4 (DMODEL * DMODEL / 4)         // 262144  (1<<18)
__global__ __launch_bounds__(256) void split_all(
    const float* __restrict__ x,
    const float* __restrict__ wq, const float* __restrict__ wk,
    const float* __restrict__ wv,
    short* __restrict__ Xhi, short* __restrict__ Xlo,
    short* __restrict__ Whi, short* __restrict__ Wlo)
{
    int gid = blockIdx.x * 256 + threadIdx.x;
    const float* src; short* dh; short* dl; int off;
    if (gid < X_F4) {
        src = x; dh = Xhi; dl = Xlo; off = gid;
    } else {
        int r = gid - X_F4;
        int z = r >> 18;                   // 0..2
        off = r & (W_F4 - 1);
        src = (z == 0) ? wq : (z == 1) ? wk : wv;
        dh = Whi + (size_t)z * DMODEL * DMODEL;
        dl = Wlo + (size_t)z * DMODEL * DMODEL;
    }
    float4 v = ((const float4*)src)[off];
    float f[4] = {v.x, v.y, v.z, v.w};
    short h[4], l[4];
    #pragma unroll
    for (int c = 0; c < 4; c++) {
        h[c] = f2bf(f[c]);
        l[c] = f2bf(f[c] - bf2f(h[c]));
    }
    *(float2*)(dh + (size_t)off * 4) = *(const float2*)h;
    *(float2*)(dl + (size_t)off * 4) = *(const float2*)l;
}

// ---------------------------------------------------------------------------
// Split-bf16 MFMA GEMM: Y = X W^T + b.  (R0 two-barrier structure, 32 KB LDS)
// z=0 -> Qhi/Qlo bf16 [bh][T][64] (scaled by QSCALE)   3-MFMA split
// z=1 -> Khi/Klo bf16 [bh][T][64]                      3-MFMA split
// z=2 -> V^T   fp16  [bh][64][T]   single bf16 MFMA
// R3: XCD-chunked block swizzle (T1). HW: xcd = linear_wgid % 8, x fastest.
//     Remap so XCD c owns m-tiles 8c..8c+7 with n cycling fastest ->
//     the 0.5 MB X A-panel stays L2-hot instead of being fetched by all
//     8 XCDs. 512 % 8 == 0 -> bijective.
// ---------------------------------------------------------------------------
__global__ __launch_bounds__(256, 2) void qkv_gemm_mfma(
    const short* __restrict__ Xhi, const short* __restrict__ Xlo,
    const short* __restrict__ Wh3, const short* __restrict__ Wl3,  // [3][N][K]
    const float* __restrict__ bq, const float* __restrict__ bk,
    const float* __restrict__ bv,
    short* __restrict__ Qhi, short* __restrict__ Qlo,
    short* __restrict__ Khi, short* __restrict__ Klo,
    _Float16* __restrict__ VgT)
{
    const int z = blockIdx.z;
    const bool dolo = (z != 2);
    const short* Wh = Wh3 + (size_t)z * DMODEL * DMODEL;
    const short* Wl = Wl3 + (size_t)z * DMODEL * DMODEL;
    const float* bias = (z == 0) ? bq : (z == 1) ? bk : bv;

    __shared__ __align__(16) short Ah[128 * 32];
    __shared__ __align__(16) short Al[128 * 32];
    __shared__ __align__(16) short Bh[128 * 32];
    __shared__ __align__(16) short Bl[128 * 32];

    const int tid  = threadIdx.x;
    const int w    = tid >> 6;
    const int lane = tid & 63;
    const int t    = lane & 15;
    const int quad = lane >> 4;
    const int wm   = w >> 1, wn = w & 1;

    // XCD-chunked swizzle: orig in hw dispatch order (x fastest), 512 blocks
    const int orig = blockIdx.x + (blockIdx.y << 3);       // 0..511
    const int nw   = (orig & 7) * 64 + (orig >> 3);        // bijective remap
    const int bm   = (nw >> 3) * 128;                      // m-tile 0..63
    const int bn   = (nw & 7) * 128;                       // n-tile 0..7

    const int r_local = lane >> 2;
    const int kq      = (lane & 3) ^ ((r_local >> 1) & 3);
    const int row0    = w * 32 + r_local;
    const int slotq   = (quad ^ ((t >> 1) & 3)) * 8;

    f32x4 acc[4][4];
    #pragma unroll
    for (int i = 0; i < 4; i++)
        #pragma unroll
        for (int j = 0; j < 4; j++) acc[i][j] = (f32x4){0.f, 0.f, 0.f, 0.f};

    for (int k0 = 0; k0 < DMODEL; k0 += 32) {
        __syncthreads();
        #pragma unroll
        for (int i = 0; i < 2; i++) {
            int row = row0 + i * 16;
            size_t ga = (size_t)(bm + row) * DMODEL + k0 + kq * 8;
            size_t gb = (size_t)(bn + row) * DMODEL + k0 + kq * 8;
            int ldst = (w * 32 + i * 16) * 32;
            async_copy16(&Ah[ldst], Xhi + ga);
            async_copy16(&Bh[ldst], Wh + gb);
            if (dolo) {
                async_copy16(&Al[ldst], Xlo + ga);
                async_copy16(&Bl[ldst], Wl + gb);
            }
        }
        __syncthreads();

        bf16x8 ah[4], al[4], bh[4], bl[4];
        #pragma unroll
        for (int mt = 0; mt < 4; mt++) {
            int off = (wm * 64 + mt * 16 + t) * 32 + slotq;
            ah[mt] = *(const bf16x8*)&Ah[off];
            if (dolo) al[mt] = *(const bf16x8*)&Al[off];
        }
        #pragma unroll
        for (int nt = 0; nt < 4; nt++) {
            int off = (wn * 64 + nt * 16 + t) * 32 + slotq;
            bh[nt] = *(const bf16x8*)&Bh[off];
            if (dolo) bl[nt] = *(const bf16x8*)&Bl[off];
        }
        #pragma unroll
        for (int mt = 0; mt < 4; mt++)
            #pragma unroll
            for (int nt = 0; nt < 4; nt++) {
                if (dolo) {
                    acc[mt][nt] = __builtin_amdgcn_mfma_f32_16x16x32_bf16(
                        al[mt], bh[nt], acc[mt][nt], 0, 0, 0);
                    acc[mt][nt] = __builtin_amdgcn_mfma_f32_16x16x32_bf16(
                        ah[mt], bl[nt], acc[mt][nt], 0, 0, 0);
                }
                acc[mt][nt] = __builtin_amdgcn_mfma_f32_16x16x32_bf16(
                    ah[mt], bh[nt], acc[mt][nt], 0, 0, 0);
            }
    }

    const float scale = (z == 0) ? QSCALE : 1.0f;
    const int n_base = bn + wn * 64;
    const int h_head = n_base >> 6;
    float bvs[4];
    #pragma unroll
    for (int nt = 0; nt < 4; nt++)
        bvs[nt] = bias[n_base + nt * 16 + t];

    #pragma unroll
    for (int mt = 0; mt < 4; mt++) {
        #pragma unroll
        for (int r = 0; r < 4; r++) {
            int m  = bm + wm * 64 + mt * 16 + quad * 4 + r;
            int b_ = m >> 11;
            int t_ = m & 2047;
            #pragma unroll
            for (int nt = 0; nt < 4; nt++) {
                int d = nt * 16 + t;
                float v = (acc[mt][nt][r] + bvs[nt]) * scale;
                if (z == 2) {
                    size_t idx = ((size_t)(b_ * NHEAD + h_head) * HDIM + d) * TSEQ + t_;
                    VgT[idx] = (_Float16)v;
                } else {
                    size_t idx = (((size_t)(b_ * NHEAD + h_head) * TSEQ + t_) << 6) + d;
                    short hb = f2bf(v);
                    short lb = f2bf(v - bf2f(hb));
                    if (z == 0) { Qhi[idx] = hb; Qlo[idx] = lb; }
                    else        { Khi[idx] = hb; Klo[idx] = lb; }
                }
            }
        }
    }
}

// ---------------------------------------------------------------------------
// MFMA flash attention v5 — pair-batched softmax + BALANCED GRID.
//  Block (i, bh), i in [0,8): processes Q-tile i (i+1 pairs) then Q-tile
//  15-i (16-i pairs) -> every block does exactly 17 pair-units.
// R3: XCD-chunked swizzle — XCD c owns bh 8c..8c+7 with the tile selector
//     cycling fastest, so the 0.75 MB K/V set per bh stays L2-hot.
//     + s_setprio(1) around MFMA clusters (T5, m191: +4-7% on attn).
// LDS: 2*(8+8+8) + 18 = 66 KB -> 2 blocks/CU.
// ---------------------------------------------------------------------------
__global__ __launch_bounds__(256, 2) void attn_fwd(
    const short* __restrict__ Qhi, const short* __restrict__ Qlo,
    const short* __restrict__ Khi, const short* __restrict__ Klo,
    const _Float16* __restrict__ VgT,   // [bh][64][T]
    float* __restrict__ out)            // [B][T][1024]
{
    __shared__ __align__(16) short    Kh_lds[2][64 * 64];
    __shared__ __align__(16) short    Kl_lds[2][64 * 64];
    __shared__ __align__(16) _Float16 Vt_lds[2][64 * 64];
    __shared__ __align__(16) _Float16 P_lds [128 * 72];

    const int tid  = threadIdx.x;

    // XCD-chunked swizzle (8 x 64 grid, x fastest in hw order)
    const int orig = blockIdx.x + (blockIdx.y << 3);       // 0..511
    const int nw   = (orig & 7) * 64 + (orig >> 3);        // bijective remap
    const int bh   = nw >> 3;                              // 0..63
    const int xt   = nw & 7;                               // 0..7 tile selector

    const int b    = bh >> 4, h = bh & 15;
    const int w    = tid >> 6;
    const int lane = tid & 63;
    const int t    = lane & 15;
    const int quad = lane >> 4;

    // staging geometry: per round, 256 lanes x 16B = 32 rows of 128B.
    const int rl      = w * 8 + (lane >> 3);         // 0..31 within round
    const int chsw    = (lane & 7) ^ ((lane >> 3) & 7);
    const int ld_off  = (w * 8) * 64;                // wave-uniform LDS base

    const size_t kbase = (size_t)bh * TSEQ;          // K rows
    const size_t vbase = (size_t)bh * HDIM;          // V^T rows

    // read-side swizzled chunk offsets: chunk g=dh*4+quad at slot g^(t&7)
    const int rs0 = ((0 * 4 + quad) ^ (t & 7)) * 8;
    const int rs1 = ((1 * 4 + quad) ^ (t & 7)) * 8;

    f16x8 ones;
    #pragma unroll
    for (int i = 0; i < 8; i++) ones[i] = (_Float16)1.0f;

    auto stage = [&](int kt, int bf) {
        #pragma unroll
        for (int i = 0; i < 2; i++) {
            int row = i * 32 + rl;
            const short* gk = Khi + (kbase + kt * 64 + row) * 64 + chsw * 8;
            async_copy16(&Kh_lds[bf][(i * 32) * 64 + ld_off], gk);
            const short* gl = Klo + (kbase + kt * 64 + row) * 64 + chsw * 8;
            async_copy16(&Kl_lds[bf][(i * 32) * 64 + ld_off], gl);
            const _Float16* gv = VgT + (vbase + row) * TSEQ + kt * 64 + chsw * 8;
            async_copy16(&Vt_lds[bf][(i * 32) * 64 + ld_off], gv);
        }
    };

    // two complementary Q-tile segments: i+1 pairs, then 16-i pairs (17 total)
    #pragma unroll 1
    for (int seg = 0; seg < 2; seg++) {
        const int qb = seg ? (15 - xt) : xt;

        // Q A-frags for this segment
        bf16x8 qh[2][2], ql[2][2];
        #pragma unroll
        for (int mt = 0; mt < 2; mt++) {
            size_t qrow = kbase + qb * 128 + w * 32 + mt * 16 + t;
            #pragma unroll
            for (int dh = 0; dh < 2; dh++) {
                qh[mt][dh] = *(const bf16x8*)(Qhi + qrow * 64 + dh * 32 + quad * 8);
                ql[mt][dh] = *(const bf16x8*)(Qlo + qrow * 64 + dh * 32 + quad * 8);
            }
        }

        f32x4 O[2][4], Ol[2];
        #pragma unroll
        for (int mt = 0; mt < 2; mt++) {
            Ol[mt] = (f32x4){0.f, 0.f, 0.f, 0.f};
            #pragma unroll
            for (int j = 0; j < 4; j++) O[mt][j] = (f32x4){0.f, 0.f, 0.f, 0.f};
        }
        float m_st[2][4];
        #pragma unroll
        for (int mt = 0; mt < 2; mt++)
            #pragma unroll
            for (int r = 0; r < 4; r++) m_st[mt][r] = -1e30f;

        const int npair = qb + 1;

        #pragma unroll 1
        for (int p = 0; p < npair; p++) {
            __syncthreads();              // previous pair's LDS reads complete
            stage(2 * p, 0);
            stage(2 * p + 1, 1);
            __syncthreads();              // drain the 12 async copies

            #pragma unroll
            for (int mt = 0; mt < 2; mt++) {
                // ---- S over 128 cols: c8=0..3 from buf0, 4..7 from buf1 ----
                f32x4 S[8];
                __builtin_amdgcn_s_setprio(1);
                #pragma unroll
                for (int c8 = 0; c8 < 8; c8++) {
                    S[c8] = (f32x4){0.f, 0.f, 0.f, 0.f};
                    const int bf = c8 >> 2;
                    const int rowoff = ((c8 & 3) * 16 + t) * 64;
                    {
                        bf16x8 kh = *(const bf16x8*)&Kh_lds[bf][rowoff + rs0];
                        bf16x8 kl = *(const bf16x8*)&Kl_lds[bf][rowoff + rs0];
                        S[c8] = __builtin_amdgcn_mfma_f32_16x16x32_bf16(ql[mt][0], kh, S[c8], 0, 0, 0);
                        S[c8] = __builtin_amdgcn_mfma_f32_16x16x32_bf16(qh[mt][0], kl, S[c8], 0, 0, 0);
                        S[c8] = __builtin_amdgcn_mfma_f32_16x16x32_bf16(qh[mt][0], kh, S[c8], 0, 0, 0);
                    }
                    {
                        bf16x8 kh = *(const bf16x8*)&Kh_lds[bf][rowoff + rs1];
                        bf16x8 kl = *(const bf16x8*)&Kl_lds[bf][rowoff + rs1];
                        S[c8] = __builtin_amdgcn_mfma_f32_16x16x32_bf16(ql[mt][1], kh, S[c8], 0, 0, 0);
                        S[c8] = __builtin_amdgcn_mfma_f32_16x16x32_bf16(qh[mt][1], kl, S[c8], 0, 0, 0);
                        S[c8] = __builtin_amdgcn_mfma_f32_16x16x32_bf16(qh[mt][1], kh, S[c8], 0, 0, 0);
                    }
                }
                __builtin_amdgcn_s_setprio(0);

                // causal mask (only the last pair contains the diagonal)
                if (p == qb) {
                    #pragma unroll
                    for (int c8 = 0; c8 < 8; c8++) {
                        int col = c8 * 16 + t;
                        #pragma unroll
                        for (int r = 0; r < 4; r++)
                            if (col > w * 32 + mt * 16 + quad * 4 + r) S[c8][r] = -1e30f;
                    }
                }

                // ---- ONE max-reduce + (conditional) rescale per 128 cols ----
                float mx[4]; bool grow = false;
                #pragma unroll
                for (int r = 0; r < 4; r++) {
                    float a0 = fmaxf(fmaxf(S[0][r], S[1][r]), fmaxf(S[2][r], S[3][r]));
                    float a1 = fmaxf(fmaxf(S[4][r], S[5][r]), fmaxf(S[6][r], S[7][r]));
                    float v = fmaxf(a0, a1);
                    v = fmaxf(v, __shfl_xor(v, 1, 64));
                    v = fmaxf(v, __shfl_xor(v, 2, 64));
                    v = fmaxf(v, __shfl_xor(v, 4, 64));
                    v = fmaxf(v, __shfl_xor(v, 8, 64));
                    mx[r] = v;
                    grow = grow || (v > m_st[mt][r]);
                }
                if (__ballot(grow)) {
                    #pragma unroll
                    for (int r = 0; r < 4; r++) {
                        float mn = fmaxf(m_st[mt][r], mx[r]);
                        float al = exp2f(m_st[mt][r] - mn);
                        m_st[mt][r] = mn;
                        Ol[mt][r] *= al;
                        #pragma unroll
                        for (int ct2 = 0; ct2 < 4; ct2++) O[mt][ct2][r] *= al;
                    }
                }
                #pragma unroll
                for (int c8 = 0; c8 < 8; c8++)
                    #pragma unroll
                    for (int r = 0; r < 4; r++)
                        S[c8][r] = exp2f(S[c8][r] - m_st[mt][r]);

                // ---- PV in two halves, reusing the wave-private P strip ----
                const int prow = w * 32 + mt * 16;
                #pragma unroll
                for (int half = 0; half < 2; half++) {
                    #pragma unroll
                    for (int ct = 0; ct < 4; ct++)
                        #pragma unroll
                        for (int r = 0; r < 4; r++)
                            P_lds[(prow + quad * 4 + r) * 72 + ct * 16 + t] =
                                (_Float16)S[half * 4 + ct][r];
                    f16x8 p0 = *(const f16x8*)&P_lds[(prow + t) * 72 + quad * 8];
                    f16x8 p1 = *(const f16x8*)&P_lds[(prow + t) * 72 + 32 + quad * 8];
                    __builtin_amdgcn_s_setprio(1);
                    #pragma unroll
                    for (int ct2 = 0; ct2 < 4; ct2++) {
                        int rowoff2 = (ct2 * 16 + t) * 64;
                        f16x8 v0 = *(const f16x8*)&Vt_lds[half][rowoff2 + rs0];
                        f16x8 v1 = *(const f16x8*)&Vt_lds[half][rowoff2 + rs1];
                        O[mt][ct2] = __builtin_amdgcn_mfma_f32_16x16x32_f16(p0, v0, O[mt][ct2], 0, 0, 0);
                        O[mt][ct2] = __builtin_amdgcn_mfma_f32_16x16x32_f16(p1, v1, O[mt][ct2], 0, 0, 0);
                    }
                    Ol[mt] = __builtin_amdgcn_mfma_f32_16x16x32_f16(p0, ones, Ol[mt], 0, 0, 0);
                    Ol[mt] = __builtin_amdgcn_mfma_f32_16x16x32_f16(p1, ones, Ol[mt], 0, 0, 0);
                    __builtin_amdgcn_s_setprio(0);
                }
            }
        }

        // epilogue: normalize, write [B][T][H*64] fp32
        #pragma unroll
        for (int mt = 0; mt < 2; mt++) {
            float* ob = out + ((size_t)b * TSEQ + qb * 128 + w * 32 + mt * 16 + quad * 4) * DMODEL
                      + h * 64;
            #pragma unroll
            for (int r = 0; r < 4; r++) {
                float inv = 1.0f / Ol[mt][r];
                #pragma unroll
                for (int ct2 = 0; ct2 < 4; ct2++)
                    ob[(size_t)r * DMODEL + ct2 * 16 + t] = O[mt][ct2][r] * inv;
            }
        }
    }
}

// ---------------------------------------------------------------------------
extern "C" void kernel_launch(void* const* d_in, const int* in_sizes, int n_in,
                              void* d_out, int out_size, void* d_ws, size_t ws_size,
                              hipStream_t stream)
{
    const float* x  = (const float*)d_in[0];
    const float* Wq = (const float*)d_in[1];
    const float* bq = (const float*)d_in[2];
    const float* Wk = (const float*)d_in[3];
    const float* bk = (const float*)d_in[4];
    const float* Wv = (const float*)d_in[5];
    const float* bv = (const float*)d_in[6];

    const size_t TEN = (size_t)MROWS * DMODEL;   // 8M
    const size_t WEN = (size_t)DMODEL * DMODEL;  // 1M
    short* Xhi = (short*)d_ws;
    short* Xlo = Xhi + TEN;
    short* Whi = Xlo + TEN;
    short* Wlo = Whi + 3 * WEN;
    short* Qhi = Wlo + 3 * WEN;
    short* Qlo = Qhi + TEN;
    short* Khi = Qlo + TEN;
    short* Klo = Khi + TEN;
    _Float16* VgT = (_Float16*)(Klo + TEN);
    float* out = (float*)d_out;

    int nsplit = (X_F4 + 3 * W_F4) / 256;
    split_all<<<nsplit, 256, 0, stream>>>(x, Wq, Wk, Wv, Xhi, Xlo, Whi, Wlo);

    dim3 gg(DMODEL / 128, MROWS / 128, 3);
    qkv_gemm_mfma<<<gg, 256, 0, stream>>>(Xhi, Xlo, Whi, Wlo, bq, bk, bv,
                                          Qhi, Qlo, Khi, Klo, VgT);

    dim3 ga(8, NBATCH * NHEAD);
    attn_fwd<<<ga, 256, 0, stream>>>(Qhi, Qlo, Khi, Klo, VgT, out);
}

// Round 4
// 349.757 us; speedup vs baseline: 1.1248x; 1.0312x over previous
//
#include <hip/hip_runtime.h>
#include <math.h>

#define TSEQ   2048
#define NBATCH 4
#define NHEAD  16
#define HDIM   64
#define DMODEL 1024
#define MROWS  (NBATCH * TSEQ)   // 8192
// fold 8 * log2(e) into Q so softmax runs in exp2 domain (v_exp_f32 native)
#define QSCALE 11.541560327111707f

typedef float f32x4  __attribute__((ext_vector_type(4)));
typedef short bf16x8 __attribute__((ext_vector_type(8)));
typedef _Float16 f16x8 __attribute__((ext_vector_type(8)));

static __device__ __forceinline__ short f2bf(float f) {  // RNE float->bf16
    union { float f; unsigned u; } a; a.f = f;
    unsigned r = a.u + 0x7FFFu + ((a.u >> 16) & 1u);
    return (short)(r >> 16);
}
static __device__ __forceinline__ float bf2f(short s) {
    union { unsigned u; float f; } a; a.u = ((unsigned)(unsigned short)s) << 16;
    return a.f;
}
// RNE f32 pair -> packed 2x f16 in a u32
static __device__ __forceinline__ unsigned pkh(float a, float b) {
    union { _Float16 h[2]; unsigned u; } z;
    z.h[0] = (_Float16)a; z.h[1] = (_Float16)b;
    return z.u;
}

// async global->LDS, 16B per lane; LDS dest = wave-uniform base + lane*16
static __device__ __forceinline__ void async_copy16(void* lds, const void* g) {
    __builtin_amdgcn_global_load_lds(
        (const __attribute__((address_space(1))) void*)g,
        (__attribute__((address_space(3))) void*)lds, 16, 0, 0);
}

// ---------------------------------------------------------------------------
// One fused fp32 -> (hi,lo) bf16 splitter for X, Wq, Wk, Wv.
// ---------------------------------------------------------------------------
#define X_F4 (MROWS * DMODEL / 4)          // 2097152
#define W_F4 (DMODEL * DMODEL / 4)         // 262144  (1<<18)
__global__ __launch_bounds__(256) void split_all(
    const float* __restrict__ x,
    const float* __restrict__ wq, const float* __restrict__ wk,
    const float* __restrict__ wv,
    short* __restrict__ Xhi, short* __restrict__ Xlo,
    short* __restrict__ Whi, short* __restrict__ Wlo)
{
    int gid = blockIdx.x * 256 + threadIdx.x;
    const float* src; short* dh; short* dl; int off;
    if (gid < X_F4) {
        src = x; dh = Xhi; dl = Xlo; off = gid;
    } else {
        int r = gid - X_F4;
        int z = r >> 18;                   // 0..2
        off = r & (W_F4 - 1);
        src = (z == 0) ? wq : (z == 1) ? wk : wv;
        dh = Whi + (size_t)z * DMODEL * DMODEL;
        dl = Wlo + (size_t)z * DMODEL * DMODEL;
    }
    float4 v = ((const float4*)src)[off];
    float f[4] = {v.x, v.y, v.z, v.w};
    short h[4], l[4];
    #pragma unroll
    for (int c = 0; c < 4; c++) {
        h[c] = f2bf(f[c]);
        l[c] = f2bf(f[c] - bf2f(h[c]));
    }
    *(float2*)(dh + (size_t)off * 4) = *(const float2*)h;
    *(float2*)(dl + (size_t)off * 4) = *(const float2*)l;
}

// ---------------------------------------------------------------------------
// Split-bf16 MFMA GEMM: Y = X W^T + b.  (R0 two-barrier structure, 32 KB LDS)
// R3: XCD-chunked block swizzle (T1) — kept, FETCH dropped and qkv left the
//     top-5.
// ---------------------------------------------------------------------------
__global__ __launch_bounds__(256, 2) void qkv_gemm_mfma(
    const short* __restrict__ Xhi, const short* __restrict__ Xlo,
    const short* __restrict__ Wh3, const short* __restrict__ Wl3,  // [3][N][K]
    const float* __restrict__ bq, const float* __restrict__ bk,
    const float* __restrict__ bv,
    short* __restrict__ Qhi, short* __restrict__ Qlo,
    short* __restrict__ Khi, short* __restrict__ Klo,
    _Float16* __restrict__ VgT)
{
    const int z = blockIdx.z;
    const bool dolo = (z != 2);
    const short* Wh = Wh3 + (size_t)z * DMODEL * DMODEL;
    const short* Wl = Wl3 + (size_t)z * DMODEL * DMODEL;
    const float* bias = (z == 0) ? bq : (z == 1) ? bk : bv;

    __shared__ __align__(16) short Ah[128 * 32];
    __shared__ __align__(16) short Al[128 * 32];
    __shared__ __align__(16) short Bh[128 * 32];
    __shared__ __align__(16) short Bl[128 * 32];

    const int tid  = threadIdx.x;
    const int w    = tid >> 6;
    const int lane = tid & 63;
    const int t    = lane & 15;
    const int quad = lane >> 4;
    const int wm   = w >> 1, wn = w & 1;

    // XCD-chunked swizzle: orig in hw dispatch order (x fastest), 512 blocks
    const int orig = blockIdx.x + (blockIdx.y << 3);       // 0..511
    const int nw   = (orig & 7) * 64 + (orig >> 3);        // bijective remap
    const int bm   = (nw >> 3) * 128;                      // m-tile 0..63
    const int bn   = (nw & 7) * 128;                       // n-tile 0..7

    const int r_local = lane >> 2;
    const int kq      = (lane & 3) ^ ((r_local >> 1) & 3);
    const int row0    = w * 32 + r_local;
    const int slotq   = (quad ^ ((t >> 1) & 3)) * 8;

    f32x4 acc[4][4];
    #pragma unroll
    for (int i = 0; i < 4; i++)
        #pragma unroll
        for (int j = 0; j < 4; j++) acc[i][j] = (f32x4){0.f, 0.f, 0.f, 0.f};

    for (int k0 = 0; k0 < DMODEL; k0 += 32) {
        __syncthreads();
        #pragma unroll
        for (int i = 0; i < 2; i++) {
            int row = row0 + i * 16;
            size_t ga = (size_t)(bm + row) * DMODEL + k0 + kq * 8;
            size_t gb = (size_t)(bn + row) * DMODEL + k0 + kq * 8;
            int ldst = (w * 32 + i * 16) * 32;
            async_copy16(&Ah[ldst], Xhi + ga);
            async_copy16(&Bh[ldst], Wh + gb);
            if (dolo) {
                async_copy16(&Al[ldst], Xlo + ga);
                async_copy16(&Bl[ldst], Wl + gb);
            }
        }
        __syncthreads();

        bf16x8 ah[4], al[4], bh[4], bl[4];
        #pragma unroll
        for (int mt = 0; mt < 4; mt++) {
            int off = (wm * 64 + mt * 16 + t) * 32 + slotq;
            ah[mt] = *(const bf16x8*)&Ah[off];
            if (dolo) al[mt] = *(const bf16x8*)&Al[off];
        }
        #pragma unroll
        for (int nt = 0; nt < 4; nt++) {
            int off = (wn * 64 + nt * 16 + t) * 32 + slotq;
            bh[nt] = *(const bf16x8*)&Bh[off];
            if (dolo) bl[nt] = *(const bf16x8*)&Bl[off];
        }
        #pragma unroll
        for (int mt = 0; mt < 4; mt++)
            #pragma unroll
            for (int nt = 0; nt < 4; nt++) {
                if (dolo) {
                    acc[mt][nt] = __builtin_amdgcn_mfma_f32_16x16x32_bf16(
                        al[mt], bh[nt], acc[mt][nt], 0, 0, 0);
                    acc[mt][nt] = __builtin_amdgcn_mfma_f32_16x16x32_bf16(
                        ah[mt], bl[nt], acc[mt][nt], 0, 0, 0);
                }
                acc[mt][nt] = __builtin_amdgcn_mfma_f32_16x16x32_bf16(
                    ah[mt], bh[nt], acc[mt][nt], 0, 0, 0);
            }
    }

    const float scale = (z == 0) ? QSCALE : 1.0f;
    const int n_base = bn + wn * 64;
    const int h_head = n_base >> 6;
    float bvs[4];
    #pragma unroll
    for (int nt = 0; nt < 4; nt++)
        bvs[nt] = bias[n_base + nt * 16 + t];

    #pragma unroll
    for (int mt = 0; mt < 4; mt++) {
        #pragma unroll
        for (int r = 0; r < 4; r++) {
            int m  = bm + wm * 64 + mt * 16 + quad * 4 + r;
            int b_ = m >> 11;
            int t_ = m & 2047;
            #pragma unroll
            for (int nt = 0; nt < 4; nt++) {
                int d = nt * 16 + t;
                float v = (acc[mt][nt][r] + bvs[nt]) * scale;
                if (z == 2) {
                    size_t idx = ((size_t)(b_ * NHEAD + h_head) * HDIM + d) * TSEQ + t_;
                    VgT[idx] = (_Float16)v;
                } else {
                    size_t idx = (((size_t)(b_ * NHEAD + h_head) * TSEQ + t_) << 6) + d;
                    short hb = f2bf(v);
                    short lb = f2bf(v - bf2f(hb));
                    if (z == 0) { Qhi[idx] = hb; Qlo[idx] = lb; }
                    else        { Khi[idx] = hb; Klo[idx] = lb; }
                }
            }
        }
    }
}

// ---------------------------------------------------------------------------
// MFMA flash attention v6 — SWAPPED QK^T + in-register P (no P_lds).
//  S^T = mfma(K,Q): A/B frag layouts are lane-symmetric for 16x16x32, so
//  LDS reads are unchanged; output has q = t lane-local.
//  - row-max: in-lane over 32 + shfl_xor(16,32)          (was 4x(tree+4 shfl))
//  - P->A-frag: 16 pack + 16 shfl_xor(16) + 16 selects   (was 64 cvt +
//    64 ds_write_b16 + 4 ds_read_b128 per mt)
//    residual quad-bit swap folded into the V read-chunk permutation (qsw).
//  - denominator via ones-MFMA (lands in O's C-layout directly)
//  - rescale factor crosses S^T->O domain via 4 shfls, gated by defer-max
//    (T13, THR=8 in exp2 domain; P <= 2^8 safe in f16)
// LDS: 2*(8+8+8) = 48 KB -> 2 blocks/CU (grid=512=2/CU).
// ---------------------------------------------------------------------------
__global__ __launch_bounds__(256, 2) void attn_fwd(
    const short* __restrict__ Qhi, const short* __restrict__ Qlo,
    const short* __restrict__ Khi, const short* __restrict__ Klo,
    const _Float16* __restrict__ VgT,   // [bh][64][T]
    float* __restrict__ out)            // [B][T][1024]
{
    __shared__ __align__(16) short    Kh_lds[2][64 * 64];
    __shared__ __align__(16) short    Kl_lds[2][64 * 64];
    __shared__ __align__(16) _Float16 Vt_lds[2][64 * 64];

    const int tid  = threadIdx.x;

    // XCD-chunked swizzle (8 x 64 grid, x fastest in hw order)
    const int orig = blockIdx.x + (blockIdx.y << 3);       // 0..511
    const int nw   = (orig & 7) * 64 + (orig >> 3);        // bijective remap
    const int bh   = nw >> 3;                              // 0..63
    const int xt   = nw & 7;                               // 0..7 tile selector

    const int b    = bh >> 4, h = bh & 15;
    const int w    = tid >> 6;
    const int lane = tid & 63;
    const int t    = lane & 15;
    const int quad = lane >> 4;

    // staging geometry: per round, 256 lanes x 16B = 32 rows of 128B.
    const int rl      = w * 8 + (lane >> 3);         // 0..31 within round
    const int chsw    = (lane & 7) ^ ((lane >> 3) & 7);
    const int ld_off  = (w * 8) * 64;                // wave-uniform LDS base

    const size_t kbase = (size_t)bh * TSEQ;          // K rows
    const size_t vbase = (size_t)bh * HDIM;          // V^T rows

    // K read chunks (unchanged): logical chunk g = dh*4+quad at slot g^(t&7)
    const int rs0 = ((0 * 4 + quad) ^ (t & 7)) * 8;
    const int rs1 = ((1 * 4 + quad) ^ (t & 7)) * 8;
    // V read chunks for PV: quad bits SWAPPED (absorbs the 2nd exchange step)
    const int qsw = ((quad & 1) << 1) | (quad >> 1);
    const int rp0 = ((0 * 4 + qsw) ^ (t & 7)) * 8;
    const int rp1 = ((1 * 4 + qsw) ^ (t & 7)) * 8;
    const bool hi4 = (quad & 1);                     // lane bit4

    f16x8 ones;
    #pragma unroll
    for (int i = 0; i < 8; i++) ones[i] = (_Float16)1.0f;

    auto stage = [&](int kt, int bf) {
        #pragma unroll
        for (int i = 0; i < 2; i++) {
            int row = i * 32 + rl;
            const short* gk = Khi + (kbase + kt * 64 + row) * 64 + chsw * 8;
            async_copy16(&Kh_lds[bf][(i * 32) * 64 + ld_off], gk);
            const short* gl = Klo + (kbase + kt * 64 + row) * 64 + chsw * 8;
            async_copy16(&Kl_lds[bf][(i * 32) * 64 + ld_off], gl);
            const _Float16* gv = VgT + (vbase + row) * TSEQ + kt * 64 + chsw * 8;
            async_copy16(&Vt_lds[bf][(i * 32) * 64 + ld_off], gv);
        }
    };

    // two complementary Q-tile segments: i+1 pairs, then 16-i pairs (17 total)
    #pragma unroll 1
    for (int seg = 0; seg < 2; seg++) {
        const int qb = seg ? (15 - xt) : xt;

        // Q frags for this segment (used as B-operand in swapped QK^T)
        bf16x8 qh[2][2], ql[2][2];
        #pragma unroll
        for (int mt = 0; mt < 2; mt++) {
            size_t qrow = kbase + qb * 128 + w * 32 + mt * 16 + t;
            #pragma unroll
            for (int dh = 0; dh < 2; dh++) {
                qh[mt][dh] = *(const bf16x8*)(Qhi + qrow * 64 + dh * 32 + quad * 8);
                ql[mt][dh] = *(const bf16x8*)(Qlo + qrow * 64 + dh * 32 + quad * 8);
            }
        }

        f32x4 O[2][4], Ol[2];
        #pragma unroll
        for (int mt = 0; mt < 2; mt++) {
            Ol[mt] = (f32x4){0.f, 0.f, 0.f, 0.f};
            #pragma unroll
            for (int j = 0; j < 4; j++) O[mt][j] = (f32x4){0.f, 0.f, 0.f, 0.f};
        }
        float m_st[2];
        m_st[0] = -1e30f; m_st[1] = -1e30f;

        const int npair = qb + 1;

        #pragma unroll 1
        for (int p = 0; p < npair; p++) {
            __syncthreads();              // previous pair's LDS reads complete
            stage(2 * p, 0);
            stage(2 * p + 1, 1);
            __syncthreads();              // drain the 12 async copies

            #pragma unroll
            for (int mt = 0; mt < 2; mt++) {
                // ---- S^T over 128 kv: S[c8][r] = S[kp=c8*16+quad*4+r][q=t]
                f32x4 S[8];
                __builtin_amdgcn_s_setprio(1);
                #pragma unroll
                for (int c8 = 0; c8 < 8; c8++) {
                    S[c8] = (f32x4){0.f, 0.f, 0.f, 0.f};
                    const int bf = c8 >> 2;
                    const int rowoff = ((c8 & 3) * 16 + t) * 64;
                    {
                        bf16x8 kh = *(const bf16x8*)&Kh_lds[bf][rowoff + rs0];
                        bf16x8 kl = *(const bf16x8*)&Kl_lds[bf][rowoff + rs0];
                        S[c8] = __builtin_amdgcn_mfma_f32_16x16x32_bf16(kh, ql[mt][0], S[c8], 0, 0, 0);
                        S[c8] = __builtin_amdgcn_mfma_f32_16x16x32_bf16(kl, qh[mt][0], S[c8], 0, 0, 0);
                        S[c8] = __builtin_amdgcn_mfma_f32_16x16x32_bf16(kh, qh[mt][0], S[c8], 0, 0, 0);
                    }
                    {
                        bf16x8 kh = *(const bf16x8*)&Kh_lds[bf][rowoff + rs1];
                        bf16x8 kl = *(const bf16x8*)&Kl_lds[bf][rowoff + rs1];
                        S[c8] = __builtin_amdgcn_mfma_f32_16x16x32_bf16(kh, ql[mt][1], S[c8], 0, 0, 0);
                        S[c8] = __builtin_amdgcn_mfma_f32_16x16x32_bf16(kl, qh[mt][1], S[c8], 0, 0, 0);
                        S[c8] = __builtin_amdgcn_mfma_f32_16x16x32_bf16(kh, qh[mt][1], S[c8], 0, 0, 0);
                    }
                }
                __builtin_amdgcn_s_setprio(0);

                // causal mask: kp > q  (only the diagonal pair)
                if (p == qb) {
                    const int qloc = w * 32 + mt * 16 + t;
                    #pragma unroll
                    for (int c8 = 0; c8 < 8; c8++) {
                        int kp = c8 * 16 + quad * 4;
                        #pragma unroll
                        for (int r = 0; r < 4; r++)
                            if (kp + r > qloc) S[c8][r] = -1e30f;
                    }
                }

                // ---- row max: in-lane 32 + cross-quad (2 shfl) ----
                float mx = S[0][0];
                #pragma unroll
                for (int c8 = 0; c8 < 8; c8++)
                    #pragma unroll
                    for (int r = 0; r < 4; r++)
                        mx = fmaxf(mx, S[c8][r]);
                mx = fmaxf(mx, __shfl_xor(mx, 16));
                mx = fmaxf(mx, __shfl_xor(mx, 32));

                // ---- defer-max rescale (THR=8 in exp2 domain) ----
                bool need = mx > m_st[mt] + 8.0f;
                if (__ballot(need)) {
                    float mn = fmaxf(m_st[mt], mx);
                    float al = exp2f(m_st[mt] - mn);
                    m_st[mt] = mn;
                    #pragma unroll
                    for (int r = 0; r < 4; r++) {
                        // O rows live at q = quad*4+r; al lives at lane t=q
                        float a = __shfl(al, (lane & 48) + quad * 4 + r);
                        Ol[mt][r] *= a;
                        #pragma unroll
                        for (int ct2 = 0; ct2 < 4; ct2++) O[mt][ct2][r] *= a;
                    }
                }

                #pragma unroll
                for (int c8 = 0; c8 < 8; c8++)
                    #pragma unroll
                    for (int r = 0; r < 4; r++)
                        S[c8][r] = exp2f(S[c8][r] - m_st[mt]);

                // ---- pack P to f16 pairs: P2[c8][rp] = (r=2rp, r=2rp+1) ----
                unsigned P2[8][2];
                #pragma unroll
                for (int c8 = 0; c8 < 8; c8++) {
                    P2[c8][0] = pkh(S[c8][0], S[c8][1]);
                    P2[c8][1] = pkh(S[c8][2], S[c8][3]);
                }

                // ---- step-A exchange: swap lane bit4 with c8 bit0 ----
                // frag[tau] slots: [s0rp0, s0rp1, s1rp0, s1rp1]
                unsigned FR[4][4];
                #pragma unroll
                for (int tau = 0; tau < 4; tau++) {
                    #pragma unroll
                    for (int rp = 0; rp < 2; rp++) {
                        unsigned X  = P2[2 * tau][rp];
                        unsigned Y  = P2[2 * tau + 1][rp];
                        unsigned Xs = (unsigned)__shfl_xor((int)X, 16);
                        unsigned Ys = (unsigned)__shfl_xor((int)Y, 16);
                        FR[tau][rp]     = hi4 ? Ys : X;   // slot s=0
                        FR[tau][2 + rp] = hi4 ? Y  : Xs;  // slot s=1
                    }
                }

                // ---- PV: 4 k-tiles of 32, V read with quad-swapped chunks --
                #pragma unroll
                for (int tau = 0; tau < 4; tau++) {
                    union { unsigned u[4]; f16x8 v; } pu;
                    pu.u[0] = FR[tau][0]; pu.u[1] = FR[tau][1];
                    pu.u[2] = FR[tau][2]; pu.u[3] = FR[tau][3];
                    f16x8 pf = pu.v;
                    const int bf  = tau >> 1;
                    const int rsP = (tau & 1) ? rp1 : rp0;
                    __builtin_amdgcn_s_setprio(1);
                    #pragma unroll
                    for (int ct2 = 0; ct2 < 4; ct2++) {
                        f16x8 v = *(const f16x8*)&Vt_lds[bf][(ct2 * 16 + t) * 64 + rsP];
                        O[mt][ct2] = __builtin_amdgcn_mfma_f32_16x16x32_f16(pf, v, O[mt][ct2], 0, 0, 0);
                    }
                    Ol[mt] = __builtin_amdgcn_mfma_f32_16x16x32_f16(pf, ones, Ol[mt], 0, 0, 0);
                    __builtin_amdgcn_s_setprio(0);
                }
            }
        }

        // epilogue: normalize, write [B][T][H*64] fp32 (O layout unchanged)
        #pragma unroll
        for (int mt = 0; mt < 2; mt++) {
            float* ob = out + ((size_t)b * TSEQ + qb * 128 + w * 32 + mt * 16 + quad * 4) * DMODEL
                      + h * 64;
            #pragma unroll
            for (int r = 0; r < 4; r++) {
                float inv = 1.0f / Ol[mt][r];
                #pragma unroll
                for (int ct2 = 0; ct2 < 4; ct2++)
                    ob[(size_t)r * DMODEL + ct2 * 16 + t] = O[mt][ct2][r] * inv;
            }
        }
    }
}

// ---------------------------------------------------------------------------
extern "C" void kernel_launch(void* const* d_in, const int* in_sizes, int n_in,
                              void* d_out, int out_size, void* d_ws, size_t ws_size,
                              hipStream_t stream)
{
    const float* x  = (const float*)d_in[0];
    const float* Wq = (const float*)d_in[1];
    const float* bq = (const float*)d_in[2];
    const float* Wk = (const float*)d_in[3];
    const float* bk = (const float*)d_in[4];
    const float* Wv = (const float*)d_in[5];
    const float* bv = (const float*)d_in[6];

    const size_t TEN = (size_t)MROWS * DMODEL;   // 8M
    const size_t WEN = (size_t)DMODEL * DMODEL;  // 1M
    short* Xhi = (short*)d_ws;
    short* Xlo = Xhi + TEN;
    short* Whi = Xlo + TEN;
    short* Wlo = Whi + 3 * WEN;
    short* Qhi = Wlo + 3 * WEN;
    short* Qlo = Qhi + TEN;
    short* Khi = Qlo + TEN;
    short* Klo = Khi + TEN;
    _Float16* VgT = (_Float16*)(Klo + TEN);
    float* out = (float*)d_out;

    int nsplit = (X_F4 + 3 * W_F4) / 256;
    split_all<<<nsplit, 256, 0, stream>>>(x, Wq, Wk, Wv, Xhi, Xlo, Whi, Wlo);

    dim3 gg(DMODEL / 128, MROWS / 128, 3);
    qkv_gemm_mfma<<<gg, 256, 0, stream>>>(Xhi, Xlo, Whi, Wlo, bq, bk, bv,
                                          Qhi, Qlo, Khi, Klo, VgT);

    dim3 ga(8, NBATCH * NHEAD);
    attn_fwd<<<ga, 256, 0, stream>>>(Qhi, Qlo, Khi, Klo, VgT, out);
}